// Round 1
// baseline (6075.962 us; speedup 1.0000x reference)
//
#include <hip/hip_runtime.h>
#include <cstdint>
#include <cstddef>

#define EDIM 256
#define HID  512
#define NTAG 12
#define HDIM 256
#define BB   64
#define SS   256
#define START_TAG 10
#define STOP_TAG  11
#define NEGV (-10000.0f)

// ---------------- K0: embedding gather  x[t][b][k] = emb[sent[b][t]][k] ----
__global__ void k0_gather(const int* __restrict__ sent,
                          const float* __restrict__ emb,
                          float* __restrict__ xbuf) {
  int t = blockIdx.x;
  for (int n = threadIdx.x; n < BB * EDIM; n += 256) {
    int b = n >> 8, k = n & 255;
    int tok = sent[b * SS + t];
    xbuf[((size_t)t * BB + b) * EDIM + k] = emb[(size_t)tok * EDIM + k];
  }
}

// ---------------- K1: input projection, pre[d][t][w][i][b] ----------------
// row mapping for owner-WG w, local row i in [0,16): gate g=i>>2, unit j=i&3
// global gate row R = g*256 + w*4 + j
__global__ void __launch_bounds__(256)
k1_inproj(const float* __restrict__ xbuf,
          const float* __restrict__ WihF, const float* __restrict__ WihB,
          const float* __restrict__ bihF, const float* __restrict__ bhhF,
          const float* __restrict__ bihB, const float* __restrict__ bhhB,
          float* __restrict__ pre) {
  int blk = blockIdx.x;               // ((d*256)+t)*16 + wq
  int wq = blk & 15;
  int t  = (blk >> 4) & 255;
  int d  = blk >> 12;
  const float* Wih = d ? WihB : WihF;
  const float* bi  = d ? bihB : bihF;
  const float* bh  = d ? bhhB : bhhF;
  __shared__ float Wl[64][EDIM];      // 64 KB
  int tid = threadIdx.x;
  for (int r = 0; r < 64; ++r) {      // r = wi*16 + i  (wi in [0,4))
    int wi = r >> 4, i = r & 15;
    int R = ((i >> 2) << 8) + ((wq * 4 + wi) << 2) + (i & 3);
    Wl[r][tid] = Wih[(size_t)R * EDIM + tid];
  }
  __syncthreads();
  int rr = tid >> 4, bb = tid & 15;   // thread covers rows rr+{0,16,32,48}=a*16+rr, b bb+{0,16,32,48}
  float acc[4][4];
  for (int a = 0; a < 4; ++a) {       // row r64=a*16+rr -> wi=a, i=rr
    int R = ((rr >> 2) << 8) + ((wq * 4 + a) << 2) + (rr & 3);
    float bias = bi[R] + bh[R];
    for (int c = 0; c < 4; ++c) acc[a][c] = bias;
  }
  const float* xt = xbuf + (size_t)t * BB * EDIM;
  for (int k = 0; k < EDIM; k += 4) {
    float4 xv[4];
#pragma unroll
    for (int c = 0; c < 4; ++c)
      xv[c] = *(const float4*)&xt[(size_t)(bb + c * 16) * EDIM + k];
#pragma unroll
    for (int a = 0; a < 4; ++a) {
      float4 wv = *(const float4*)&Wl[rr + a * 16][k];
#pragma unroll
      for (int c = 0; c < 4; ++c) {
        acc[a][c] += wv.x * xv[c].x;
        acc[a][c] += wv.y * xv[c].y;
        acc[a][c] += wv.z * xv[c].z;
        acc[a][c] += wv.w * xv[c].w;
      }
    }
  }
  size_t base = (((size_t)d * SS + t) * 64) * 16 * BB;
  for (int a = 0; a < 4; ++a)
    for (int c = 0; c < 4; ++c)
      pre[base + ((size_t)(wq * 4 + a) * 16 + rr) * BB + (bb + c * 16)] = acc[a][c];
}

// ---------------- K2: persistent bidirectional LSTM -----------------------
// 128 WGs: d = bid>>6, w = bid&63. WG owns hidden units [w*4, w*4+4)
// (16 gate rows). Per-direction monotonic barrier through agent atomics.
__global__ void __launch_bounds__(512, 1)
lstm_persist(const float* __restrict__ WhhF, const float* __restrict__ WhhB,
             const float* __restrict__ h0, const float* __restrict__ c0,
             const float* __restrict__ pre,
             float* __restrict__ hseq, float* hx, unsigned int* ctr) {
  int bid = blockIdx.x;
  int d = bid >> 6, w = bid & 63;
  int tid = threadIdx.x;
  __shared__ float Wl[16][HDIM];      // 16 KB
  __shared__ float hl[HDIM][BB];      // 64 KB
  __shared__ float prl[16][BB];       // 4 KB
  __shared__ float cl[4][BB];         // 1 KB
  const float* Whh = d ? WhhB : WhhF;
  for (int i = 0; i < 16; ++i) {
    int R = ((i >> 2) << 8) + (w << 2) + (i & 3);
    for (int k = tid; k < HDIM; k += 512) Wl[i][k] = Whh[(size_t)R * HDIM + k];
  }
  if (tid < 256) {
    int j = tid >> 6, b = tid & 63;
    cl[j][b] = c0[(size_t)d * BB * HDIM + (size_t)b * HDIM + (w * 4 + j)];
  }
  __syncthreads();
  unsigned int* myctr = ctr + d * 32;

  for (int s = 0; s < SS; ++s) {
    int t = d ? (SS - 1 - s) : s;
    // ---- 1) load h_{s-1} into LDS
    if (s == 0) {
      for (int n = tid; n < HDIM * BB; n += 512) {
        int k = n >> 6, b = n & 63;
        hl[k][b] = h0[(size_t)d * BB * HDIM + (size_t)b * HDIM + k];
      }
    } else {
      if (tid == 0) {
        unsigned int target = 64u * (unsigned int)s;
        while (__hip_atomic_load(myctr, __ATOMIC_RELAXED, __HIP_MEMORY_SCOPE_AGENT) < target)
          __builtin_amdgcn_s_sleep(4);
      }
      __builtin_amdgcn_fence(__ATOMIC_ACQUIRE, "agent");
      __syncthreads();
      unsigned long long* src8 =
          (unsigned long long*)(hx + (((size_t)d * 2 + (s & 1)) * HDIM * BB));
      unsigned long long* dst8 = (unsigned long long*)(&hl[0][0]);
#pragma unroll
      for (int p = 0; p < 16; ++p) {
        int idx = p * 512 + tid;      // pair index < 8192
        dst8[idx] = __hip_atomic_load(src8 + idx, __ATOMIC_RELAXED, __HIP_MEMORY_SCOPE_AGENT);
      }
    }
    __syncthreads();
    // ---- 2) gate pre-activations: 16 rows x 64 batch
    {
      int r = tid >> 5, b2 = tid & 31;
      const float* pr = pre + ((((size_t)d * SS + t) * 64 + w) * 16) * BB;
      float a0 = pr[r * BB + b2], a1 = pr[r * BB + b2 + 32];
#pragma unroll 4
      for (int k = 0; k < HDIM; ++k) {
        float wv = Wl[r][k];
        a0 += wv * hl[k][b2];
        a1 += wv * hl[k][b2 + 32];
      }
      prl[r][b2] = a0; prl[r][b2 + 32] = a1;
    }
    __syncthreads();
    // ---- 3) activations (i,f,g,o rows are prl[j], prl[4+j], prl[8+j], prl[12+j])
    if (tid < 256) {
      int j = tid >> 6, b = tid & 63;
      float iv = prl[j][b], fvv = prl[4 + j][b], gv = prl[8 + j][b], ov = prl[12 + j][b];
      float si = 1.f / (1.f + expf(-iv));
      float sf = 1.f / (1.f + expf(-fvv));
      float so = 1.f / (1.f + expf(-ov));
      float cn = sf * cl[j][b] + si * tanhf(gv);
      cl[j][b] = cn;
      float hn = so * tanhf(cn);
      int kg = w * 4 + j;
      hseq[(((size_t)d * SS + t) * HDIM + kg) * BB + b] = hn;
      float* dst = hx + (((size_t)d * 2 + ((s + 1) & 1)) * HDIM * BB) + (size_t)kg * BB + b;
      __hip_atomic_store(dst, hn, __ATOMIC_RELAXED, __HIP_MEMORY_SCOPE_AGENT);
    }
    __syncthreads();
    if (tid == 0)
      __hip_atomic_fetch_add(myctr, 1u, __ATOMIC_RELEASE, __HIP_MEMORY_SCOPE_AGENT);
  }
}

// ---------------- K3: feats[t][b][tag] = [hf;hb] . Wt[tag] + bt -----------
__global__ void k3_feats(const float* __restrict__ hseq,
                         const float* __restrict__ Wt,
                         const float* __restrict__ bt,
                         float* __restrict__ feats) {
  int t = blockIdx.x, tid = threadIdx.x;
  __shared__ float Wl[NTAG][HID];     // 24 KB
  for (int n = tid; n < NTAG * HID; n += 256) Wl[n >> 9][n & 511] = Wt[n];
  __syncthreads();
  int b = tid & 63, tq = tid >> 6;    // 3 tags per thread
  float acc[3];
  for (int c = 0; c < 3; ++c) acc[c] = bt[tq * 3 + c];
  const float* hf = hseq + ((size_t)0 * SS + t) * HDIM * BB;
  const float* hb = hseq + ((size_t)1 * SS + t) * HDIM * BB;
  for (int k = 0; k < HDIM; ++k) {
    float h1 = hf[(size_t)k * BB + b];
    float h2 = hb[(size_t)k * BB + b];
#pragma unroll
    for (int c = 0; c < 3; ++c) {
      acc[c] += h1 * Wl[tq * 3 + c][k];
      acc[c] += h2 * Wl[tq * 3 + c][HDIM + k];
    }
  }
  for (int c = 0; c < 3; ++c)
    feats[((size_t)t * BB + b) * NTAG + tq * 3 + c] = acc[c];
}

// ---------------- K4: Viterbi per batch element ---------------------------
__global__ void k4_viterbi(const float* __restrict__ feats,
                           const float* __restrict__ trans,
                           float* __restrict__ out) {
  int b = blockIdx.x, lane = threadIdx.x;   // 64 threads
  __shared__ float tr[NTAG][NTAG];
  __shared__ float fv[NTAG], fnew[NTAG], term[NTAG];
  __shared__ unsigned char bp[SS][NTAG];
  for (int n = lane; n < NTAG * NTAG; n += 64) tr[n / NTAG][n % NTAG] = trans[n];
  if (lane < NTAG) fv[lane] = (lane == START_TAG) ? 0.f : NEGV;
  __syncthreads();
  for (int s = 0; s < SS; ++s) {
    if (lane < NTAG) {
      float best = fv[0] + tr[lane][0]; int arg = 0;
#pragma unroll
      for (int j = 1; j < NTAG; ++j) {
        float v = fv[j] + tr[lane][j];
        if (v > best) { best = v; arg = j; }   // strict > keeps first max (jnp.argmax)
      }
      fnew[lane] = best + feats[((size_t)s * BB + b) * NTAG + lane];
      bp[s][lane] = (unsigned char)arg;
    }
    __syncthreads();
    if (lane < NTAG) fv[lane] = fnew[lane];
    __syncthreads();
  }
  if (lane < NTAG) {
    float v = fv[lane] + tr[STOP_TAG][lane];
    if (lane == STOP_TAG || lane == START_TAG) v = NEGV;
    term[lane] = v;
  }
  __syncthreads();
  if (lane == 0) {
    float best = term[0]; int arg = 0;
    for (int j = 1; j < NTAG; ++j)
      if (term[j] > best) { best = term[j]; arg = j; }
    out[b] = best;
    int cur = arg;
    for (int s = SS - 1; s >= 0; --s) {
      out[64 + (size_t)b * SS + s] = (float)cur;
      cur = bp[s][cur];
    }
  }
}

// ---------------- launch ---------------------------------------------------
extern "C" void kernel_launch(void* const* d_in, const int* in_sizes, int n_in,
                              void* d_out, int out_size, void* d_ws, size_t ws_size,
                              hipStream_t stream) {
  (void)in_sizes; (void)n_in; (void)out_size;
  const int*   sent  = (const int*)d_in[0];
  const float* emb   = (const float*)d_in[4];
  const float* WihF  = (const float*)d_in[5];
  const float* WhhF  = (const float*)d_in[6];
  const float* bihF  = (const float*)d_in[7];
  const float* bhhF  = (const float*)d_in[8];
  const float* WihB  = (const float*)d_in[9];
  const float* WhhB  = (const float*)d_in[10];
  const float* bihB  = (const float*)d_in[11];
  const float* bhhB  = (const float*)d_in[12];
  const float* Wt    = (const float*)d_in[13];
  const float* bt    = (const float*)d_in[14];
  const float* trans = (const float*)d_in[15];
  const float* h0    = (const float*)d_in[16];
  const float* c0    = (const float*)d_in[17];
  float* out = (float*)d_out;

  char* ws = (char*)d_ws;
  // layout: ctr(256) | xbuf 16MB | pre 128MB | hseq 32MB | hx 512KB | feats 768KB
  unsigned int* ctr = (unsigned int*)ws;
  float* xbuf  = (float*)(ws + 256);
  float* pre   = (float*)(ws + 256 + 16777216ull);
  float* hseq  = (float*)(ws + 256 + 16777216ull + 134217728ull);
  float* hx    = (float*)(ws + 256 + 16777216ull + 134217728ull + 33554432ull);
  float* feats = (float*)(ws + 256 + 16777216ull + 134217728ull + 33554432ull + 524288ull);
  if (ws_size < 185860352ull) return;  // need ~178 MiB scratch

  hipMemsetAsync(ctr, 0, 256, stream);
  k0_gather<<<SS, 256, 0, stream>>>(sent, emb, xbuf);
  k1_inproj<<<8192, 256, 0, stream>>>(xbuf, WihF, WihB, bihF, bhhF, bihB, bhhB, pre);
  lstm_persist<<<128, 512, 0, stream>>>(WhhF, WhhB, h0, c0, pre, hseq, hx, ctr);
  k3_feats<<<SS, 256, 0, stream>>>(hseq, Wt, bt, feats);
  k4_viterbi<<<BB, 64, 0, stream>>>(feats, trans, out);
}

// Round 2
// 3387.967 us; speedup vs baseline: 1.7934x; 1.7934x over previous
//
#include <hip/hip_runtime.h>
#include <cstdint>
#include <cstddef>

#define EDIM 256
#define HID  512
#define NTAG 12
#define HDIM 256
#define BB   64
#define SS   256
#define START_TAG 10
#define STOP_TAG  11
#define NEGV (-10000.0f)
#define NWGD 32          // workgroups per direction
#define UPW  8           // h-units per WG (32 gate rows)

typedef __attribute__((ext_vector_type(8))) short bf16x8;
typedef __attribute__((ext_vector_type(4))) float f32x4;

__device__ __forceinline__ unsigned short bf16_rne(float x) {
  union { float f; unsigned u; } a; a.f = x;
  return (unsigned short)((a.u + 0x7fffu + ((a.u >> 16) & 1u)) >> 16);
}
__device__ __forceinline__ float bf16_tof(unsigned short h) {
  union { unsigned u; float f; } a; a.u = ((unsigned)h) << 16; return a.f;
}

// ---------------- K0: embedding gather  x[t][b][k] = emb[sent[b][t]][k] ----
__global__ void k0_gather(const int* __restrict__ sent,
                          const float* __restrict__ emb,
                          float* __restrict__ xbuf) {
  int t = blockIdx.x;
  for (int n = threadIdx.x; n < BB * EDIM; n += 256) {
    int b = n >> 8, k = n & 255;
    int tok = sent[b * SS + t];
    xbuf[((size_t)t * BB + b) * EDIM + k] = emb[(size_t)tok * EDIM + k];
  }
}

// ---------------- K1: input projection -> pre[d][t][R][b], R=g*256+unit ---
__global__ void __launch_bounds__(256)
k1_inproj(const float* __restrict__ xbuf,
          const float* __restrict__ WihF, const float* __restrict__ WihB,
          const float* __restrict__ bihF, const float* __restrict__ bhhF,
          const float* __restrict__ bihB, const float* __restrict__ bhhB,
          float* __restrict__ pre) {
  int blk = blockIdx.x;               // ((d*256)+t)*16 + wq
  int wq = blk & 15;
  int t  = (blk >> 4) & 255;
  int d  = blk >> 12;
  const float* Wih = d ? WihB : WihF;
  const float* bi  = d ? bihB : bihF;
  const float* bh  = d ? bhhB : bhhF;
  __shared__ float Wl[64][EDIM];      // 64 KB
  int tid = threadIdx.x;
  for (int r = 0; r < 64; ++r) {
    int wi = r >> 4, i = r & 15;
    int R = ((i >> 2) << 8) + ((wq * 4 + wi) << 2) + (i & 3);
    Wl[r][tid] = Wih[(size_t)R * EDIM + tid];
  }
  __syncthreads();
  int rr = tid >> 4, bb = tid & 15;
  float acc[4][4];
  for (int a = 0; a < 4; ++a) {
    int R = ((rr >> 2) << 8) + ((wq * 4 + a) << 2) + (rr & 3);
    float bias = bi[R] + bh[R];
    for (int c = 0; c < 4; ++c) acc[a][c] = bias;
  }
  const float* xt = xbuf + (size_t)t * BB * EDIM;
  for (int k = 0; k < EDIM; k += 4) {
    float4 xv[4];
#pragma unroll
    for (int c = 0; c < 4; ++c)
      xv[c] = *(const float4*)&xt[(size_t)(bb + c * 16) * EDIM + k];
#pragma unroll
    for (int a = 0; a < 4; ++a) {
      float4 wv = *(const float4*)&Wl[rr + a * 16][k];
#pragma unroll
      for (int c = 0; c < 4; ++c) {
        acc[a][c] += wv.x * xv[c].x;
        acc[a][c] += wv.y * xv[c].y;
        acc[a][c] += wv.z * xv[c].z;
        acc[a][c] += wv.w * xv[c].w;
      }
    }
  }
  size_t base = ((size_t)d * SS + t) * 1024 * BB;
  for (int a = 0; a < 4; ++a)
    for (int c = 0; c < 4; ++c) {
      int R = ((rr >> 2) << 8) + ((wq * 4 + a) << 2) + (rr & 3);
      pre[base + (size_t)R * BB + (bb + c * 16)] = acc[a][c];
    }
}

// ---------------- K2: persistent BiLSTM with split-bf16 MFMA ---------------
// 64 WGs: d = bid>>5, w = bid&31. WG owns h-units [w*8, w*8+8) => 32 gate
// rows (i = g*8+u, global R = g*256 + w*8 + u). 4 waves; wave v owns batch
// cols [v*16, v*16+16). A (Whh hi/lo) register-resident. h exchanged as
// packed u32 (bf16 hi | lo<<16) via agent atomics + per-direction counter.
__global__ void __launch_bounds__(256, 1)
lstm_mfma(const float* __restrict__ WhhF, const float* __restrict__ WhhB,
          const float* __restrict__ h0, const float* __restrict__ c0,
          const float* __restrict__ pre, float* __restrict__ hseq,
          unsigned int* __restrict__ hx, unsigned int* ctr) {
  const int bid = blockIdx.x;
  const int d = bid >> 5, w = bid & 31;
  const int tid = threadIdx.x;
  const int lane = tid & 63;
  const int v = tid >> 6;            // wave id 0..3
  const int l15 = lane & 15, l4 = lane >> 4;
  const float* Whh = d ? WhhB : WhhF;

  __shared__ float Cl[32][65];       // gate preacts (padded: conflict-free)
  __shared__ float cst[UPW][BB];     // cell state

  // ---- persistent A fragments: A[i][k], i = rt*16+l15, k = kk*32+l4*8+j
  bf16x8 Ahi[2][8], Alo[2][8];
#pragma unroll
  for (int rt = 0; rt < 2; ++rt) {
    int i = rt * 16 + l15;
    int R = ((i >> 3) << 8) + w * UPW + (i & 7);
    const float* wrow = Whh + (size_t)R * HDIM;
#pragma unroll
    for (int kk = 0; kk < 8; ++kk) {
      float4 f0 = *(const float4*)(wrow + kk * 32 + l4 * 8);
      float4 f1 = *(const float4*)(wrow + kk * 32 + l4 * 8 + 4);
      float xf[8] = {f0.x, f0.y, f0.z, f0.w, f1.x, f1.y, f1.z, f1.w};
      bf16x8 h8, lo8;
#pragma unroll
      for (int j = 0; j < 8; ++j) {
        unsigned short hb = bf16_rne(xf[j]);
        h8[j] = (short)hb;
        lo8[j] = (short)bf16_rne(xf[j] - bf16_tof(hb));
      }
      Ahi[rt][kk] = h8; Alo[rt][kk] = lo8;
    }
  }
  for (int n = tid; n < UPW * BB; n += 256) {
    int u = n >> 6, b = n & 63;
    cst[u][b] = c0[((size_t)d * BB + b) * HDIM + (w * UPW + u)];
  }
  __syncthreads();

  const int bcol = v * 16 + l15;     // this lane's batch column
  unsigned int* myctr = ctr + d * 32;

  for (int s = 0; s < SS; ++s) {
    const int t = d ? (SS - 1 - s) : s;

    // ---- acc init from pre: issued BEFORE the poll (hides HBM latency)
    const float* pbase = pre + (((size_t)d * SS + t) * 1024) * BB + bcol;
    f32x4 acc0, acc1;
#pragma unroll
    for (int r = 0; r < 4; ++r) {
      int i0 = l4 * 4 + r;
      int R0 = ((i0 >> 3) << 8) + w * UPW + (i0 & 7);
      acc0[r] = pbase[(size_t)R0 * BB];
      int i1 = 16 + i0;
      int R1 = ((i1 >> 3) << 8) + w * UPW + (i1 & 7);
      acc1[r] = pbase[(size_t)R1 * BB];
    }

    if (s > 0) {
      if (tid == 0) {
        unsigned int target = (unsigned int)(NWGD * s);
        while (__hip_atomic_load(myctr, __ATOMIC_RELAXED, __HIP_MEMORY_SCOPE_AGENT) < target)
          __builtin_amdgcn_s_sleep(1);
      }
      __builtin_amdgcn_fence(__ATOMIC_ACQUIRE, "agent");
    }
    __syncthreads();

    // ---- B fragments (h hi/lo) + MFMA over K=256
    if (s == 0) {
      const float* hrow = h0 + ((size_t)d * BB + bcol) * HDIM;
#pragma unroll
      for (int kk = 0; kk < 8; ++kk) {
        float4 f0 = *(const float4*)(hrow + kk * 32 + l4 * 8);
        float4 f1 = *(const float4*)(hrow + kk * 32 + l4 * 8 + 4);
        float xf[8] = {f0.x, f0.y, f0.z, f0.w, f1.x, f1.y, f1.z, f1.w};
        bf16x8 bh, bl;
#pragma unroll
        for (int j = 0; j < 8; ++j) {
          unsigned short hb = bf16_rne(xf[j]);
          bh[j] = (short)hb;
          bl[j] = (short)bf16_rne(xf[j] - bf16_tof(hb));
        }
        acc0 = __builtin_amdgcn_mfma_f32_16x16x32_bf16(Ahi[0][kk], bh, acc0, 0, 0, 0);
        acc0 = __builtin_amdgcn_mfma_f32_16x16x32_bf16(Ahi[0][kk], bl, acc0, 0, 0, 0);
        acc0 = __builtin_amdgcn_mfma_f32_16x16x32_bf16(Alo[0][kk], bh, acc0, 0, 0, 0);
        acc1 = __builtin_amdgcn_mfma_f32_16x16x32_bf16(Ahi[1][kk], bh, acc1, 0, 0, 0);
        acc1 = __builtin_amdgcn_mfma_f32_16x16x32_bf16(Ahi[1][kk], bl, acc1, 0, 0, 0);
        acc1 = __builtin_amdgcn_mfma_f32_16x16x32_bf16(Alo[1][kk], bh, acc1, 0, 0, 0);
      }
    } else {
      const unsigned int* prow =
          hx + (((size_t)d * 2 + (s & 1)) * BB + bcol) * HDIM;
#pragma unroll
      for (int kk = 0; kk < 8; ++kk) {
        const unsigned long long* p8 =
            (const unsigned long long*)(prow + kk * 32 + l4 * 8);
        unsigned long long q0 = __hip_atomic_load(p8 + 0, __ATOMIC_RELAXED, __HIP_MEMORY_SCOPE_AGENT);
        unsigned long long q1 = __hip_atomic_load(p8 + 1, __ATOMIC_RELAXED, __HIP_MEMORY_SCOPE_AGENT);
        unsigned long long q2 = __hip_atomic_load(p8 + 2, __ATOMIC_RELAXED, __HIP_MEMORY_SCOPE_AGENT);
        unsigned long long q3 = __hip_atomic_load(p8 + 3, __ATOMIC_RELAXED, __HIP_MEMORY_SCOPE_AGENT);
        unsigned wv[8] = {(unsigned)q0, (unsigned)(q0 >> 32),
                          (unsigned)q1, (unsigned)(q1 >> 32),
                          (unsigned)q2, (unsigned)(q2 >> 32),
                          (unsigned)q3, (unsigned)(q3 >> 32)};
        bf16x8 bh, bl;
#pragma unroll
        for (int j = 0; j < 8; ++j) {
          bh[j] = (short)(wv[j] & 0xffffu);
          bl[j] = (short)(wv[j] >> 16);
        }
        acc0 = __builtin_amdgcn_mfma_f32_16x16x32_bf16(Ahi[0][kk], bh, acc0, 0, 0, 0);
        acc0 = __builtin_amdgcn_mfma_f32_16x16x32_bf16(Ahi[0][kk], bl, acc0, 0, 0, 0);
        acc0 = __builtin_amdgcn_mfma_f32_16x16x32_bf16(Alo[0][kk], bh, acc0, 0, 0, 0);
        acc1 = __builtin_amdgcn_mfma_f32_16x16x32_bf16(Ahi[1][kk], bh, acc1, 0, 0, 0);
        acc1 = __builtin_amdgcn_mfma_f32_16x16x32_bf16(Ahi[1][kk], bl, acc1, 0, 0, 0);
        acc1 = __builtin_amdgcn_mfma_f32_16x16x32_bf16(Alo[1][kk], bh, acc1, 0, 0, 0);
      }
    }

    // ---- C tiles -> LDS (row = l4*4+r per C/D layout, col = bcol)
#pragma unroll
    for (int r = 0; r < 4; ++r) {
      Cl[l4 * 4 + r][bcol] = acc0[r];
      Cl[16 + l4 * 4 + r][bcol] = acc1[r];
    }
    __syncthreads();

    // ---- activations: rows 0-7=i, 8-15=f, 16-23=g, 24-31=o
    {
      const int par = (s + 1) & 1;
      unsigned int* wrow = hx + (((size_t)d * 2 + par) * BB) * HDIM;
      for (int n = tid; n < UPW * BB; n += 256) {
        int u = n >> 6, b = n & 63;
        float iv = Cl[u][b], fv = Cl[8 + u][b];
        float gv = Cl[16 + u][b], ov = Cl[24 + u][b];
        float si = 1.f / (1.f + expf(-iv));
        float sf = 1.f / (1.f + expf(-fv));
        float so = 1.f / (1.f + expf(-ov));
        float cn = sf * cst[u][b] + si * tanhf(gv);
        cst[u][b] = cn;
        float hn = so * tanhf(cn);
        int kg = w * UPW + u;
        hseq[(((size_t)d * SS + t) * HDIM + kg) * BB + b] = hn;
        unsigned short hb = bf16_rne(hn);
        unsigned short lb = bf16_rne(hn - bf16_tof(hb));
        unsigned int pv = (unsigned int)hb | ((unsigned int)lb << 16);
        __hip_atomic_store(wrow + (size_t)b * HDIM + kg, pv,
                           __ATOMIC_RELAXED, __HIP_MEMORY_SCOPE_AGENT);
      }
    }
    __syncthreads();
    if (tid == 0)
      __hip_atomic_fetch_add(myctr, 1u, __ATOMIC_RELEASE, __HIP_MEMORY_SCOPE_AGENT);
  }
}

// ---------------- K3: feats[t][b][tag] = [hf;hb] . Wt[tag] + bt -----------
__global__ void k3_feats(const float* __restrict__ hseq,
                         const float* __restrict__ Wt,
                         const float* __restrict__ bt,
                         float* __restrict__ feats) {
  int t = blockIdx.x, tid = threadIdx.x;
  __shared__ float Wl[NTAG][HID];
  for (int n = tid; n < NTAG * HID; n += 256) Wl[n >> 9][n & 511] = Wt[n];
  __syncthreads();
  int b = tid & 63, tq = tid >> 6;
  float acc[3];
  for (int c = 0; c < 3; ++c) acc[c] = bt[tq * 3 + c];
  const float* hf = hseq + ((size_t)0 * SS + t) * HDIM * BB;
  const float* hb = hseq + ((size_t)1 * SS + t) * HDIM * BB;
  for (int k = 0; k < HDIM; ++k) {
    float h1 = hf[(size_t)k * BB + b];
    float h2 = hb[(size_t)k * BB + b];
#pragma unroll
    for (int c = 0; c < 3; ++c) {
      acc[c] += h1 * Wl[tq * 3 + c][k];
      acc[c] += h2 * Wl[tq * 3 + c][HDIM + k];
    }
  }
  for (int c = 0; c < 3; ++c)
    feats[((size_t)t * BB + b) * NTAG + tq * 3 + c] = acc[c];
}

// ---------------- K4: Viterbi per batch element ---------------------------
__global__ void k4_viterbi(const float* __restrict__ feats,
                           const float* __restrict__ trans,
                           float* __restrict__ out) {
  int b = blockIdx.x, lane = threadIdx.x;   // 64 threads
  __shared__ float tr[NTAG][NTAG];
  __shared__ float fv[NTAG], fnew[NTAG], term[NTAG];
  __shared__ unsigned char bp[SS][NTAG];
  for (int n = lane; n < NTAG * NTAG; n += 64) tr[n / NTAG][n % NTAG] = trans[n];
  if (lane < NTAG) fv[lane] = (lane == START_TAG) ? 0.f : NEGV;
  __syncthreads();
  for (int s = 0; s < SS; ++s) {
    if (lane < NTAG) {
      float best = fv[0] + tr[lane][0]; int arg = 0;
#pragma unroll
      for (int j = 1; j < NTAG; ++j) {
        float vv = fv[j] + tr[lane][j];
        if (vv > best) { best = vv; arg = j; }
      }
      fnew[lane] = best + feats[((size_t)s * BB + b) * NTAG + lane];
      bp[s][lane] = (unsigned char)arg;
    }
    __syncthreads();
    if (lane < NTAG) fv[lane] = fnew[lane];
    __syncthreads();
  }
  if (lane < NTAG) {
    float vv = fv[lane] + tr[STOP_TAG][lane];
    if (lane == STOP_TAG || lane == START_TAG) vv = NEGV;
    term[lane] = vv;
  }
  __syncthreads();
  if (lane == 0) {
    float best = term[0]; int arg = 0;
    for (int j = 1; j < NTAG; ++j)
      if (term[j] > best) { best = term[j]; arg = j; }
    out[b] = best;
    int cur = arg;
    for (int s = SS - 1; s >= 0; --s) {
      out[64 + (size_t)b * SS + s] = (float)cur;
      cur = bp[s][cur];
    }
  }
}

// ---------------- launch ---------------------------------------------------
extern "C" void kernel_launch(void* const* d_in, const int* in_sizes, int n_in,
                              void* d_out, int out_size, void* d_ws, size_t ws_size,
                              hipStream_t stream) {
  (void)in_sizes; (void)n_in; (void)out_size;
  const int*   sent  = (const int*)d_in[0];
  const float* emb   = (const float*)d_in[4];
  const float* WihF  = (const float*)d_in[5];
  const float* WhhF  = (const float*)d_in[6];
  const float* bihF  = (const float*)d_in[7];
  const float* bhhF  = (const float*)d_in[8];
  const float* WihB  = (const float*)d_in[9];
  const float* WhhB  = (const float*)d_in[10];
  const float* bihB  = (const float*)d_in[11];
  const float* bhhB  = (const float*)d_in[12];
  const float* Wt    = (const float*)d_in[13];
  const float* bt    = (const float*)d_in[14];
  const float* trans = (const float*)d_in[15];
  const float* h0    = (const float*)d_in[16];
  const float* c0    = (const float*)d_in[17];
  float* out = (float*)d_out;

  char* ws = (char*)d_ws;
  // layout: ctr 256B | pre 134.2MB | region{ xbuf 16MB (dead after k1)
  //         overlapped by hseq 33.5MB } | hx 512KB | feats 768KB
  unsigned int* ctr = (unsigned int*)ws;
  float* pre   = (float*)(ws + 256);
  float* hseq  = (float*)(ws + 256 + 134217728ull);
  float* xbuf  = hseq;                       // overlap: xbuf dead before lstm
  unsigned int* hx = (unsigned int*)(ws + 256 + 134217728ull + 33554432ull);
  float* feats = (float*)(ws + 256 + 134217728ull + 33554432ull + 524288ull);
  if (ws_size < 169083136ull) return;

  hipMemsetAsync(ctr, 0, 256, stream);
  k0_gather<<<SS, 256, 0, stream>>>(sent, emb, xbuf);
  k1_inproj<<<8192, 256, 0, stream>>>(xbuf, WihF, WihB, bihF, bhhF, bihB, bhhB, pre);
  lstm_mfma<<<64, 256, 0, stream>>>(WhhF, WhhB, h0, c0, pre, hseq, hx, ctr);
  k3_feats<<<SS, 256, 0, stream>>>(hseq, Wt, bt, feats);
  k4_viterbi<<<BB, 64, 0, stream>>>(feats, trans, out);
}

// Round 3
// 2901.472 us; speedup vs baseline: 2.0941x; 1.1677x over previous
//
#include <hip/hip_runtime.h>
#include <cstdint>
#include <cstddef>

#define EDIM 256
#define HID  512
#define NTAG 12
#define HDIM 256
#define BB   64
#define SS   256
#define START_TAG 10
#define STOP_TAG  11
#define NEGV (-10000.0f)
#define NWGD 32          // workgroups per direction
#define UPW  8           // h-units per WG (32 gate rows)

typedef __attribute__((ext_vector_type(8))) short bf16x8;
typedef __attribute__((ext_vector_type(4))) float f32x4;

__device__ __forceinline__ unsigned short bf16_rne(float x) {
  union { float f; unsigned u; } a; a.f = x;
  return (unsigned short)((a.u + 0x7fffu + ((a.u >> 16) & 1u)) >> 16);
}
__device__ __forceinline__ float bf16_tof(unsigned short h) {
  union { unsigned u; float f; } a; a.u = ((unsigned)h) << 16; return a.f;
}
__device__ __forceinline__ void unpack8(const unsigned* u, bf16x8& hi, bf16x8& lo) {
#pragma unroll
  for (int j = 0; j < 8; ++j) {
    hi[j] = (short)(u[j] & 0xffffu);
    lo[j] = (short)(u[j] >> 16);
  }
}
__device__ __forceinline__ void pack_hilo(const float* xf, bf16x8& hi, bf16x8& lo) {
#pragma unroll
  for (int j = 0; j < 8; ++j) {
    unsigned short hb = bf16_rne(xf[j]);
    hi[j] = (short)hb;
    lo[j] = (short)bf16_rne(xf[j] - bf16_tof(hb));
  }
}

// ---------------- K0: gather + split-bf16 pack  xpk[t][b][k] ---------------
__global__ void k0_gather(const int* __restrict__ sent,
                          const float* __restrict__ emb,
                          unsigned int* __restrict__ xpk) {
  int t = blockIdx.x;
  for (int n = threadIdx.x; n < BB * EDIM; n += 256) {
    int b = n >> 8, k = n & 255;
    int tok = sent[b * SS + t];
    float x = emb[(size_t)tok * EDIM + k];
    unsigned short hb = bf16_rne(x);
    unsigned short lb = bf16_rne(x - bf16_tof(hb));
    xpk[((size_t)t * BB + b) * EDIM + k] = (unsigned)hb | ((unsigned)lb << 16);
  }
}

// ---------------- K1: input projection via split-bf16 MFMA ----------------
// pre[d][t][R][b], R = gate*256 + unit (PyTorch row order). Grid 8192 WGs:
// blk = ((d*256)+t)*16 + rg. Wave v owns rows rg*64+v*16..+16, loops 4
// col-tiles of 16 batch cols.
__global__ void __launch_bounds__(256)
k1_mfma(const unsigned int* __restrict__ xpk,
        const float* __restrict__ WihF, const float* __restrict__ WihB,
        const float* __restrict__ bihF, const float* __restrict__ bhhF,
        const float* __restrict__ bihB, const float* __restrict__ bhhB,
        float* __restrict__ pre) {
  int blk = blockIdx.x;
  int rg = blk & 15, t = (blk >> 4) & 255, d = blk >> 12;
  const float* Wih = d ? WihB : WihF;
  const float* bi  = d ? bihB : bihF;
  const float* bh2 = d ? bhhB : bhhF;
  int tid = threadIdx.x, lane = tid & 63, v = tid >> 6;
  int l15 = lane & 15, l4 = lane >> 4;

  // A fragments: row = rg*64 + v*16 + l15, k = kk*32 + l4*8 + j
  int Rrow = rg * 64 + v * 16 + l15;
  const float* wrow = Wih + (size_t)Rrow * EDIM;
  bf16x8 Ahi[8], Alo[8];
#pragma unroll
  for (int kk = 0; kk < 8; ++kk) {
    float4 f0 = *(const float4*)(wrow + kk * 32 + l4 * 8);
    float4 f1 = *(const float4*)(wrow + kk * 32 + l4 * 8 + 4);
    float xf[8] = {f0.x, f0.y, f0.z, f0.w, f1.x, f1.y, f1.z, f1.w};
    pack_hilo(xf, Ahi[kk], Alo[kk]);
  }
  float b4[4];
#pragma unroll
  for (int r = 0; r < 4; ++r) {
    int Racc = rg * 64 + v * 16 + l4 * 4 + r;
    b4[r] = bi[Racc] + bh2[Racc];
  }
  const unsigned int* xt = xpk + (size_t)t * BB * EDIM;
  size_t obase = ((size_t)d * SS + t) * 1024 * BB;
#pragma unroll
  for (int ct = 0; ct < 4; ++ct) {
    f32x4 acc = {b4[0], b4[1], b4[2], b4[3]};
    int col = ct * 16 + l15;
    const unsigned int* xc = xt + (size_t)col * EDIM;
#pragma unroll
    for (int kk = 0; kk < 8; ++kk) {
      uint4 q0 = *(const uint4*)(xc + kk * 32 + l4 * 8);
      uint4 q1 = *(const uint4*)(xc + kk * 32 + l4 * 8 + 4);
      unsigned u[8] = {q0.x, q0.y, q0.z, q0.w, q1.x, q1.y, q1.z, q1.w};
      bf16x8 bhf, blf;
      unpack8(u, bhf, blf);
      acc = __builtin_amdgcn_mfma_f32_16x16x32_bf16(Ahi[kk], bhf, acc, 0, 0, 0);
      acc = __builtin_amdgcn_mfma_f32_16x16x32_bf16(Ahi[kk], blf, acc, 0, 0, 0);
      acc = __builtin_amdgcn_mfma_f32_16x16x32_bf16(Alo[kk], bhf, acc, 0, 0, 0);
    }
#pragma unroll
    for (int r = 0; r < 4; ++r) {
      int Racc = rg * 64 + v * 16 + l4 * 4 + r;
      pre[obase + (size_t)Racc * BB + col] = acc[r];
    }
  }
}

// ---------------- K2: persistent BiLSTM, flag-array sync -------------------
// 64 WGs: d = bid>>5, w = bid&31. WG owns h-units [w*8, w*8+8) => 32 gate
// rows (local i = g*8+u, global R = g*256 + w*8 + u). Wave v owns batch
// cols [v*16, v*16+16). Producers release-store flags[d*32+w]=s+1 (no RMW
// contention); consumers poll all 32 flags lane-parallel.
__global__ void __launch_bounds__(256, 1)
lstm_mfma(const float* __restrict__ WhhF, const float* __restrict__ WhhB,
          const float* __restrict__ h0, const float* __restrict__ c0,
          const float* __restrict__ pre, float* __restrict__ hseq,
          unsigned int* __restrict__ hx, unsigned int* flags) {
  const int bid = blockIdx.x;
  const int d = bid >> 5, w = bid & 31;
  const int tid = threadIdx.x;
  const int lane = tid & 63;
  const int v = tid >> 6;
  const int l15 = lane & 15, l4 = lane >> 4;
  const float* Whh = d ? WhhB : WhhF;

  __shared__ float Cl[32][65];
  __shared__ float cst[UPW][BB];

  bf16x8 Ahi[2][8], Alo[2][8];
#pragma unroll
  for (int rt = 0; rt < 2; ++rt) {
    int i = rt * 16 + l15;
    int R = ((i >> 3) << 8) + w * UPW + (i & 7);
    const float* wrow = Whh + (size_t)R * HDIM;
#pragma unroll
    for (int kk = 0; kk < 8; ++kk) {
      float4 f0 = *(const float4*)(wrow + kk * 32 + l4 * 8);
      float4 f1 = *(const float4*)(wrow + kk * 32 + l4 * 8 + 4);
      float xf[8] = {f0.x, f0.y, f0.z, f0.w, f1.x, f1.y, f1.z, f1.w};
      pack_hilo(xf, Ahi[rt][kk], Alo[rt][kk]);
    }
  }
  for (int n = tid; n < UPW * BB; n += 256) {
    int u = n >> 6, b = n & 63;
    cst[u][b] = c0[((size_t)d * BB + b) * HDIM + (w * UPW + u)];
  }
  __syncthreads();

  const int bcol = v * 16 + l15;
  unsigned int* myfl = flags + d * 32;
  const int fi = lane & 31;

  for (int s = 0; s < SS; ++s) {
    const int t = d ? (SS - 1 - s) : s;

    // acc init from pre — issued BEFORE the poll to hide HBM latency
    const float* pbase = pre + (((size_t)d * SS + t) * 1024) * BB + bcol;
    f32x4 acc0, acc1;
#pragma unroll
    for (int r = 0; r < 4; ++r) {
      int i0 = l4 * 4 + r;
      int R0 = ((i0 >> 3) << 8) + w * UPW + (i0 & 7);
      acc0[r] = pbase[(size_t)R0 * BB];
      int i1 = 16 + i0;
      int R1 = ((i1 >> 3) << 8) + w * UPW + (i1 & 7);
      acc1[r] = pbase[(size_t)R1 * BB];
    }

    if (s > 0) {
      const unsigned int target = (unsigned int)s;
      const unsigned int* fp = myfl + fi;
      while (true) {
        unsigned int fv = __hip_atomic_load(fp, __ATOMIC_RELAXED, __HIP_MEMORY_SCOPE_AGENT);
        if (__all((int)(fv >= target))) break;
        __builtin_amdgcn_s_sleep(1);
      }
      __builtin_amdgcn_fence(__ATOMIC_ACQUIRE, "agent");
    }

    // B fragments (h hi/lo) + MFMA over K=256
    if (s == 0) {
      const float* hrow = h0 + ((size_t)d * BB + bcol) * HDIM;
#pragma unroll
      for (int kk = 0; kk < 8; ++kk) {
        float4 f0 = *(const float4*)(hrow + kk * 32 + l4 * 8);
        float4 f1 = *(const float4*)(hrow + kk * 32 + l4 * 8 + 4);
        float xf[8] = {f0.x, f0.y, f0.z, f0.w, f1.x, f1.y, f1.z, f1.w};
        bf16x8 bh, bl;
        pack_hilo(xf, bh, bl);
        acc0 = __builtin_amdgcn_mfma_f32_16x16x32_bf16(Ahi[0][kk], bh, acc0, 0, 0, 0);
        acc0 = __builtin_amdgcn_mfma_f32_16x16x32_bf16(Ahi[0][kk], bl, acc0, 0, 0, 0);
        acc0 = __builtin_amdgcn_mfma_f32_16x16x32_bf16(Alo[0][kk], bh, acc0, 0, 0, 0);
        acc1 = __builtin_amdgcn_mfma_f32_16x16x32_bf16(Ahi[1][kk], bh, acc1, 0, 0, 0);
        acc1 = __builtin_amdgcn_mfma_f32_16x16x32_bf16(Ahi[1][kk], bl, acc1, 0, 0, 0);
        acc1 = __builtin_amdgcn_mfma_f32_16x16x32_bf16(Alo[1][kk], bh, acc1, 0, 0, 0);
      }
    } else {
      const unsigned int* prow =
          hx + (((size_t)d * 2 + (s & 1)) * BB + bcol) * HDIM;
#pragma unroll
      for (int kk = 0; kk < 8; ++kk) {
        const unsigned long long* p8 =
            (const unsigned long long*)(prow + kk * 32 + l4 * 8);
        unsigned long long q0 = __hip_atomic_load(p8 + 0, __ATOMIC_RELAXED, __HIP_MEMORY_SCOPE_AGENT);
        unsigned long long q1 = __hip_atomic_load(p8 + 1, __ATOMIC_RELAXED, __HIP_MEMORY_SCOPE_AGENT);
        unsigned long long q2 = __hip_atomic_load(p8 + 2, __ATOMIC_RELAXED, __HIP_MEMORY_SCOPE_AGENT);
        unsigned long long q3 = __hip_atomic_load(p8 + 3, __ATOMIC_RELAXED, __HIP_MEMORY_SCOPE_AGENT);
        unsigned u[8] = {(unsigned)q0, (unsigned)(q0 >> 32),
                         (unsigned)q1, (unsigned)(q1 >> 32),
                         (unsigned)q2, (unsigned)(q2 >> 32),
                         (unsigned)q3, (unsigned)(q3 >> 32)};
        bf16x8 bh, bl;
        unpack8(u, bh, bl);
        acc0 = __builtin_amdgcn_mfma_f32_16x16x32_bf16(Ahi[0][kk], bh, acc0, 0, 0, 0);
        acc0 = __builtin_amdgcn_mfma_f32_16x16x32_bf16(Ahi[0][kk], bl, acc0, 0, 0, 0);
        acc0 = __builtin_amdgcn_mfma_f32_16x16x32_bf16(Alo[0][kk], bh, acc0, 0, 0, 0);
        acc1 = __builtin_amdgcn_mfma_f32_16x16x32_bf16(Ahi[1][kk], bh, acc1, 0, 0, 0);
        acc1 = __builtin_amdgcn_mfma_f32_16x16x32_bf16(Ahi[1][kk], bl, acc1, 0, 0, 0);
        acc1 = __builtin_amdgcn_mfma_f32_16x16x32_bf16(Alo[1][kk], bh, acc1, 0, 0, 0);
      }
    }

#pragma unroll
    for (int r = 0; r < 4; ++r) {
      Cl[l4 * 4 + r][bcol] = acc0[r];
      Cl[16 + l4 * 4 + r][bcol] = acc1[r];
    }
    __syncthreads();

    // activations: rows 0-7=i, 8-15=f, 16-23=g, 24-31=o
    {
      const int par = (s + 1) & 1;
      unsigned int* wrow = hx + (((size_t)d * 2 + par) * BB) * HDIM;
      for (int n = tid; n < UPW * BB; n += 256) {
        int u = n >> 6, b = n & 63;
        float iv = Cl[u][b], fv = Cl[8 + u][b];
        float gv = Cl[16 + u][b], ov = Cl[24 + u][b];
        float si = 1.f / (1.f + expf(-iv));
        float sf = 1.f / (1.f + expf(-fv));
        float so = 1.f / (1.f + expf(-ov));
        float cn = sf * cst[u][b] + si * tanhf(gv);
        cst[u][b] = cn;
        float hn = so * tanhf(cn);
        int kg = w * UPW + u;
        hseq[(((size_t)d * SS + t) * HDIM + kg) * BB + b] = hn;
        unsigned short hb = bf16_rne(hn);
        unsigned short lb = bf16_rne(hn - bf16_tof(hb));
        unsigned int pv = (unsigned int)hb | ((unsigned int)lb << 16);
        __hip_atomic_store(wrow + (size_t)b * HDIM + kg, pv,
                           __ATOMIC_RELAXED, __HIP_MEMORY_SCOPE_AGENT);
      }
    }
    __syncthreads();   // drains all waves' stores (vmcnt 0) before flag
    if (tid == 0)
      __hip_atomic_store(myfl + w, (unsigned int)(s + 1),
                         __ATOMIC_RELEASE, __HIP_MEMORY_SCOPE_AGENT);
  }
}

// ---------------- K3: feats[t][b][tag] = [hf;hb] . Wt[tag] + bt -----------
__global__ void k3_feats(const float* __restrict__ hseq,
                         const float* __restrict__ Wt,
                         const float* __restrict__ bt,
                         float* __restrict__ feats) {
  int t = blockIdx.x, tid = threadIdx.x;
  __shared__ float Wl[NTAG][HID];
  for (int n = tid; n < NTAG * HID; n += 256) Wl[n >> 9][n & 511] = Wt[n];
  __syncthreads();
  int b = tid & 63, tq = tid >> 6;
  float acc[3];
  for (int c = 0; c < 3; ++c) acc[c] = bt[tq * 3 + c];
  const float* hf = hseq + ((size_t)0 * SS + t) * HDIM * BB;
  const float* hb = hseq + ((size_t)1 * SS + t) * HDIM * BB;
  for (int k = 0; k < HDIM; ++k) {
    float h1 = hf[(size_t)k * BB + b];
    float h2 = hb[(size_t)k * BB + b];
#pragma unroll
    for (int c = 0; c < 3; ++c) {
      acc[c] += h1 * Wl[tq * 3 + c][k];
      acc[c] += h2 * Wl[tq * 3 + c][HDIM + k];
    }
  }
  for (int c = 0; c < 3; ++c)
    feats[((size_t)t * BB + b) * NTAG + tq * 3 + c] = acc[c];
}

// ---------------- K4: Viterbi per batch element ---------------------------
__global__ void k4_viterbi(const float* __restrict__ feats,
                           const float* __restrict__ trans,
                           float* __restrict__ out) {
  int b = blockIdx.x, lane = threadIdx.x;   // 64 threads
  __shared__ float tr[NTAG][NTAG];
  __shared__ float fv[NTAG], fnew[NTAG], term[NTAG];
  __shared__ unsigned char bp[SS][NTAG];
  for (int n = lane; n < NTAG * NTAG; n += 64) tr[n / NTAG][n % NTAG] = trans[n];
  if (lane < NTAG) fv[lane] = (lane == START_TAG) ? 0.f : NEGV;
  __syncthreads();
  for (int s = 0; s < SS; ++s) {
    if (lane < NTAG) {
      float best = fv[0] + tr[lane][0]; int arg = 0;
#pragma unroll
      for (int j = 1; j < NTAG; ++j) {
        float vv = fv[j] + tr[lane][j];
        if (vv > best) { best = vv; arg = j; }
      }
      fnew[lane] = best + feats[((size_t)s * BB + b) * NTAG + lane];
      bp[s][lane] = (unsigned char)arg;
    }
    __syncthreads();
    if (lane < NTAG) fv[lane] = fnew[lane];
    __syncthreads();
  }
  if (lane < NTAG) {
    float vv = fv[lane] + tr[STOP_TAG][lane];
    if (lane == STOP_TAG || lane == START_TAG) vv = NEGV;
    term[lane] = vv;
  }
  __syncthreads();
  if (lane == 0) {
    float best = term[0]; int arg = 0;
    for (int j = 1; j < NTAG; ++j)
      if (term[j] > best) { best = term[j]; arg = j; }
    out[b] = best;
    int cur = arg;
    for (int s = SS - 1; s >= 0; --s) {
      out[64 + (size_t)b * SS + s] = (float)cur;
      cur = bp[s][cur];
    }
  }
}

// ---------------- launch ---------------------------------------------------
extern "C" void kernel_launch(void* const* d_in, const int* in_sizes, int n_in,
                              void* d_out, int out_size, void* d_ws, size_t ws_size,
                              hipStream_t stream) {
  (void)in_sizes; (void)n_in; (void)out_size;
  const int*   sent  = (const int*)d_in[0];
  const float* emb   = (const float*)d_in[4];
  const float* WihF  = (const float*)d_in[5];
  const float* WhhF  = (const float*)d_in[6];
  const float* bihF  = (const float*)d_in[7];
  const float* bhhF  = (const float*)d_in[8];
  const float* WihB  = (const float*)d_in[9];
  const float* WhhB  = (const float*)d_in[10];
  const float* bihB  = (const float*)d_in[11];
  const float* bhhB  = (const float*)d_in[12];
  const float* Wt    = (const float*)d_in[13];
  const float* bt    = (const float*)d_in[14];
  const float* trans = (const float*)d_in[15];
  const float* h0    = (const float*)d_in[16];
  const float* c0    = (const float*)d_in[17];
  float* out = (float*)d_out;

  char* ws = (char*)d_ws;
  // layout: flags 256B | pre 134.2MB | region{ xpk 16MB (dead after k1)
  //         overlapped by hseq 33.5MB } | hx 512KB | feats 768KB
  unsigned int* flags = (unsigned int*)ws;
  float* pre   = (float*)(ws + 256);
  float* hseq  = (float*)(ws + 256 + 134217728ull);
  unsigned int* xpk = (unsigned int*)hseq;   // overlap: xpk dead before lstm
  unsigned int* hx = (unsigned int*)(ws + 256 + 134217728ull + 33554432ull);
  float* feats = (float*)(ws + 256 + 134217728ull + 33554432ull + 524288ull);
  if (ws_size < 169083136ull) return;

  hipMemsetAsync(flags, 0, 256, stream);
  k0_gather<<<SS, 256, 0, stream>>>(sent, emb, xpk);
  k1_mfma<<<8192, 256, 0, stream>>>(xpk, WihF, WihB, bihF, bhhF, bihB, bhhB, pre);
  lstm_mfma<<<64, 256, 0, stream>>>(WhhF, WhhB, h0, c0, pre, hseq, hx, flags);
  k3_feats<<<SS, 256, 0, stream>>>(hseq, Wt, bt, feats);
  k4_viterbi<<<BB, 64, 0, stream>>>(feats, trans, out);
}

// Round 4
// 1933.606 us; speedup vs baseline: 3.1423x; 1.5005x over previous
//
#include <hip/hip_runtime.h>
#include <cstdint>
#include <cstddef>

#define EDIM 256
#define HID  512
#define NTAG 12
#define HDIM 256
#define BB   64
#define SS   256
#define START_TAG 10
#define STOP_TAG  11
#define NEGV (-10000.0f)
#define NWGD 32          // workgroups per direction
#define UPW  8           // h-units per WG (32 gate rows)

typedef __attribute__((ext_vector_type(8))) short bf16x8;
typedef __attribute__((ext_vector_type(4))) float f32x4;

__device__ __forceinline__ unsigned short bf16_rne(float x) {
  union { float f; unsigned u; } a; a.f = x;
  return (unsigned short)((a.u + 0x7fffu + ((a.u >> 16) & 1u)) >> 16);
}
__device__ __forceinline__ float bf16_tof(unsigned short h) {
  union { unsigned u; float f; } a; a.u = ((unsigned)h) << 16; return a.f;
}
__device__ __forceinline__ void unpack8(const unsigned* u, bf16x8& hi, bf16x8& lo) {
#pragma unroll
  for (int j = 0; j < 8; ++j) {
    hi[j] = (short)(u[j] & 0xffffu);
    lo[j] = (short)(u[j] >> 16);
  }
}
__device__ __forceinline__ void pack_hilo(const float* xf, bf16x8& hi, bf16x8& lo) {
#pragma unroll
  for (int j = 0; j < 8; ++j) {
    unsigned short hb = bf16_rne(xf[j]);
    hi[j] = (short)hb;
    lo[j] = (short)bf16_rne(xf[j] - bf16_tof(hb));
  }
}

// ---------------- K0: gather + split-bf16 pack  xpk[t][b][k] ---------------
__global__ void k0_gather(const int* __restrict__ sent,
                          const float* __restrict__ emb,
                          unsigned int* __restrict__ xpk) {
  int t = blockIdx.x;
  for (int n = threadIdx.x; n < BB * EDIM; n += 256) {
    int b = n >> 8, k = n & 255;
    int tok = sent[b * SS + t];
    float x = emb[(size_t)tok * EDIM + k];
    unsigned short hb = bf16_rne(x);
    unsigned short lb = bf16_rne(x - bf16_tof(hb));
    xpk[((size_t)t * BB + b) * EDIM + k] = (unsigned)hb | ((unsigned)lb << 16);
  }
}

// ---------------- K1: input projection via split-bf16 MFMA ----------------
__global__ void __launch_bounds__(256)
k1_mfma(const unsigned int* __restrict__ xpk,
        const float* __restrict__ WihF, const float* __restrict__ WihB,
        const float* __restrict__ bihF, const float* __restrict__ bhhF,
        const float* __restrict__ bihB, const float* __restrict__ bhhB,
        float* __restrict__ pre) {
  int blk = blockIdx.x;
  int rg = blk & 15, t = (blk >> 4) & 255, d = blk >> 12;
  const float* Wih = d ? WihB : WihF;
  const float* bi  = d ? bihB : bihF;
  const float* bh2 = d ? bhhB : bhhF;
  int tid = threadIdx.x, lane = tid & 63, v = tid >> 6;
  int l15 = lane & 15, l4 = lane >> 4;

  int Rrow = rg * 64 + v * 16 + l15;
  const float* wrow = Wih + (size_t)Rrow * EDIM;
  bf16x8 Ahi[8], Alo[8];
#pragma unroll
  for (int kk = 0; kk < 8; ++kk) {
    float4 f0 = *(const float4*)(wrow + kk * 32 + l4 * 8);
    float4 f1 = *(const float4*)(wrow + kk * 32 + l4 * 8 + 4);
    float xf[8] = {f0.x, f0.y, f0.z, f0.w, f1.x, f1.y, f1.z, f1.w};
    pack_hilo(xf, Ahi[kk], Alo[kk]);
  }
  float b4[4];
#pragma unroll
  for (int r = 0; r < 4; ++r) {
    int Racc = rg * 64 + v * 16 + l4 * 4 + r;
    b4[r] = bi[Racc] + bh2[Racc];
  }
  const unsigned int* xt = xpk + (size_t)t * BB * EDIM;
  size_t obase = ((size_t)d * SS + t) * 1024 * BB;
#pragma unroll
  for (int ct = 0; ct < 4; ++ct) {
    f32x4 acc = {b4[0], b4[1], b4[2], b4[3]};
    int col = ct * 16 + l15;
    const unsigned int* xc = xt + (size_t)col * EDIM;
#pragma unroll
    for (int kk = 0; kk < 8; ++kk) {
      uint4 q0 = *(const uint4*)(xc + kk * 32 + l4 * 8);
      uint4 q1 = *(const uint4*)(xc + kk * 32 + l4 * 8 + 4);
      unsigned u[8] = {q0.x, q0.y, q0.z, q0.w, q1.x, q1.y, q1.z, q1.w};
      bf16x8 bhf, blf;
      unpack8(u, bhf, blf);
      acc = __builtin_amdgcn_mfma_f32_16x16x32_bf16(Ahi[kk], bhf, acc, 0, 0, 0);
      acc = __builtin_amdgcn_mfma_f32_16x16x32_bf16(Ahi[kk], blf, acc, 0, 0, 0);
      acc = __builtin_amdgcn_mfma_f32_16x16x32_bf16(Alo[kk], bhf, acc, 0, 0, 0);
    }
#pragma unroll
    for (int r = 0; r < 4; ++r) {
      int Racc = rg * 64 + v * 16 + l4 * 4 + r;
      pre[obase + (size_t)Racc * BB + col] = acc[r];
    }
  }
}

// ---------------- K2: persistent BiLSTM, fence-free UC exchange ------------
// 64 WGs: d = bid>>5, w = bid&31. WG owns h-units [w*8, w*8+8) => 32 gate
// rows. Wave v owns batch cols [v*16,v*16+16). Exchange layout hx[d][par]
// [kg][b] (coalesced). Per-WAVE flags (flags[d*128 + w*4 + v]) set after the
// wave's own s_waitcnt vmcnt(0) — no fences, no L2 wb/inv in the loop.
__global__ void __launch_bounds__(256, 1)
lstm_mfma(const float* __restrict__ WhhF, const float* __restrict__ WhhB,
          const float* __restrict__ h0, const float* __restrict__ c0,
          const float* __restrict__ pre, float* __restrict__ hseq,
          unsigned int* __restrict__ hx, unsigned int* flags) {
  const int bid = blockIdx.x;
  const int d = bid >> 5, w = bid & 31;
  const int tid = threadIdx.x;
  const int lane = tid & 63;
  const int v = tid >> 6;
  const int l15 = lane & 15, l4 = lane >> 4;
  const float* Whh = d ? WhhB : WhhF;

  __shared__ float Cl[32][65];
  __shared__ float cst[UPW][BB];

  bf16x8 Ahi[2][8], Alo[2][8];
#pragma unroll
  for (int rt = 0; rt < 2; ++rt) {
    int i = rt * 16 + l15;
    int R = ((i >> 3) << 8) + w * UPW + (i & 7);
    const float* wrow = Whh + (size_t)R * HDIM;
#pragma unroll
    for (int kk = 0; kk < 8; ++kk) {
      float4 f0 = *(const float4*)(wrow + kk * 32 + l4 * 8);
      float4 f1 = *(const float4*)(wrow + kk * 32 + l4 * 8 + 4);
      float xf[8] = {f0.x, f0.y, f0.z, f0.w, f1.x, f1.y, f1.z, f1.w};
      pack_hilo(xf, Ahi[rt][kk], Alo[rt][kk]);
    }
  }
  for (int n = tid; n < UPW * BB; n += 256) {
    int u = n >> 6, b = n & 63;
    cst[u][b] = c0[((size_t)d * BB + b) * HDIM + (w * UPW + u)];
  }
  __syncthreads();

  const int bcol = v * 16 + l15;
  unsigned int* myfl = flags + d * 128;

  for (int s = 0; s < SS; ++s) {
    const int t = d ? (SS - 1 - s) : s;

    // acc init from pre — issued BEFORE the poll to hide HBM latency
    const float* pbase = pre + (((size_t)d * SS + t) * 1024) * BB + bcol;
    f32x4 acc0, acc1;
#pragma unroll
    for (int r = 0; r < 4; ++r) {
      int i0 = l4 * 4 + r;
      int R0 = ((i0 >> 3) << 8) + w * UPW + (i0 & 7);
      acc0[r] = pbase[(size_t)R0 * BB];
      int i1 = 16 + i0;
      int R1 = ((i1 >> 3) << 8) + w * UPW + (i1 & 7);
      acc1[r] = pbase[(size_t)R1 * BB];
    }

    if (s > 0) {
      const unsigned int tgt = (unsigned int)s;
      const unsigned long long* fp = (const unsigned long long*)myfl + lane;
      while (true) {
        unsigned long long fv = __hip_atomic_load(fp, __ATOMIC_RELAXED, __HIP_MEMORY_SCOPE_AGENT);
        int ok = ((unsigned)fv >= tgt) && ((unsigned)(fv >> 32) >= tgt);
        if (__all(ok)) break;
        __builtin_amdgcn_s_sleep(1);
      }
      __builtin_amdgcn_sched_barrier(0);
    }

    // B fragments (h hi/lo) + MFMA over K=256
    if (s == 0) {
      const float* hrow = h0 + ((size_t)d * BB + bcol) * HDIM;
#pragma unroll
      for (int kk = 0; kk < 8; ++kk) {
        float4 f0 = *(const float4*)(hrow + kk * 32 + l4 * 8);
        float4 f1 = *(const float4*)(hrow + kk * 32 + l4 * 8 + 4);
        float xf[8] = {f0.x, f0.y, f0.z, f0.w, f1.x, f1.y, f1.z, f1.w};
        bf16x8 bh, bl;
        pack_hilo(xf, bh, bl);
        acc0 = __builtin_amdgcn_mfma_f32_16x16x32_bf16(Ahi[0][kk], bh, acc0, 0, 0, 0);
        acc0 = __builtin_amdgcn_mfma_f32_16x16x32_bf16(Ahi[0][kk], bl, acc0, 0, 0, 0);
        acc0 = __builtin_amdgcn_mfma_f32_16x16x32_bf16(Alo[0][kk], bh, acc0, 0, 0, 0);
        acc1 = __builtin_amdgcn_mfma_f32_16x16x32_bf16(Ahi[1][kk], bh, acc1, 0, 0, 0);
        acc1 = __builtin_amdgcn_mfma_f32_16x16x32_bf16(Ahi[1][kk], bl, acc1, 0, 0, 0);
        acc1 = __builtin_amdgcn_mfma_f32_16x16x32_bf16(Alo[1][kk], bh, acc1, 0, 0, 0);
      }
    } else {
      const unsigned int* hb_base =
          hx + (((size_t)d * 2 + (s & 1)) * HDIM) * BB + bcol;
#pragma unroll
      for (int kk = 0; kk < 8; ++kk) {
        unsigned u[8];
#pragma unroll
        for (int j = 0; j < 8; ++j)
          u[j] = __hip_atomic_load(hb_base + (size_t)(kk * 32 + l4 * 8 + j) * BB,
                                   __ATOMIC_RELAXED, __HIP_MEMORY_SCOPE_AGENT);
        bf16x8 bh, bl;
        unpack8(u, bh, bl);
        acc0 = __builtin_amdgcn_mfma_f32_16x16x32_bf16(Ahi[0][kk], bh, acc0, 0, 0, 0);
        acc0 = __builtin_amdgcn_mfma_f32_16x16x32_bf16(Ahi[0][kk], bl, acc0, 0, 0, 0);
        acc0 = __builtin_amdgcn_mfma_f32_16x16x32_bf16(Alo[0][kk], bh, acc0, 0, 0, 0);
        acc1 = __builtin_amdgcn_mfma_f32_16x16x32_bf16(Ahi[1][kk], bh, acc1, 0, 0, 0);
        acc1 = __builtin_amdgcn_mfma_f32_16x16x32_bf16(Ahi[1][kk], bl, acc1, 0, 0, 0);
        acc1 = __builtin_amdgcn_mfma_f32_16x16x32_bf16(Alo[1][kk], bh, acc1, 0, 0, 0);
      }
    }

#pragma unroll
    for (int r = 0; r < 4; ++r) {
      Cl[l4 * 4 + r][bcol] = acc0[r];
      Cl[16 + l4 * 4 + r][bcol] = acc1[r];
    }
    __syncthreads();

    // activations: wave v produces units {v, v+4} for all 64 batch cols
    {
      const int par = (s + 1) & 1;
      unsigned int* wdst = hx + (((size_t)d * 2 + par) * HDIM) * BB;
      for (int n = tid; n < UPW * BB; n += 256) {
        int u = n >> 6, b = n & 63;
        float iv = Cl[u][b], fv = Cl[8 + u][b];
        float gv = Cl[16 + u][b], ov = Cl[24 + u][b];
        float si = 1.f / (1.f + expf(-iv));
        float sf = 1.f / (1.f + expf(-fv));
        float so = 1.f / (1.f + expf(-ov));
        float cn = sf * cst[u][b] + si * tanhf(gv);
        cst[u][b] = cn;
        float hn = so * tanhf(cn);
        int kg = w * UPW + u;
        hseq[(((size_t)d * SS + t) * HDIM + kg) * BB + b] = hn;
        unsigned short hb = bf16_rne(hn);
        unsigned short lb = bf16_rne(hn - bf16_tof(hb));
        unsigned int pv = (unsigned int)hb | ((unsigned int)lb << 16);
        __hip_atomic_store(wdst + (size_t)kg * BB + b, pv,
                           __ATOMIC_RELAXED, __HIP_MEMORY_SCOPE_AGENT);
      }
    }
    // per-wave drain + per-wave flag (no __syncthreads, no fence)
    asm volatile("s_waitcnt vmcnt(0)" ::: "memory");
    if (lane == 0)
      __hip_atomic_store(myfl + w * 4 + v, (unsigned int)(s + 1),
                         __ATOMIC_RELAXED, __HIP_MEMORY_SCOPE_AGENT);
  }
}

// ---------------- K3: feats[t][b][tag] = [hf;hb] . Wt[tag] + bt -----------
__global__ void k3_feats(const float* __restrict__ hseq,
                         const float* __restrict__ Wt,
                         const float* __restrict__ bt,
                         float* __restrict__ feats) {
  int t = blockIdx.x, tid = threadIdx.x;
  __shared__ float Wl[NTAG][HID];
  for (int n = tid; n < NTAG * HID; n += 256) Wl[n >> 9][n & 511] = Wt[n];
  __syncthreads();
  int b = tid & 63, tq = tid >> 6;
  float acc[3];
  for (int c = 0; c < 3; ++c) acc[c] = bt[tq * 3 + c];
  const float* hf = hseq + ((size_t)0 * SS + t) * HDIM * BB;
  const float* hb = hseq + ((size_t)1 * SS + t) * HDIM * BB;
  for (int k = 0; k < HDIM; ++k) {
    float h1 = hf[(size_t)k * BB + b];
    float h2 = hb[(size_t)k * BB + b];
#pragma unroll
    for (int c = 0; c < 3; ++c) {
      acc[c] += h1 * Wl[tq * 3 + c][k];
      acc[c] += h2 * Wl[tq * 3 + c][HDIM + k];
    }
  }
  for (int c = 0; c < 3; ++c)
    feats[((size_t)t * BB + b) * NTAG + tq * 3 + c] = acc[c];
}

// ---------------- K4: Viterbi per batch element ---------------------------
__global__ void k4_viterbi(const float* __restrict__ feats,
                           const float* __restrict__ trans,
                           float* __restrict__ out) {
  int b = blockIdx.x, lane = threadIdx.x;   // 64 threads
  __shared__ float tr[NTAG][NTAG];
  __shared__ float fv[NTAG], fnew[NTAG], term[NTAG];
  __shared__ unsigned char bp[SS][NTAG];
  for (int n = lane; n < NTAG * NTAG; n += 64) tr[n / NTAG][n % NTAG] = trans[n];
  if (lane < NTAG) fv[lane] = (lane == START_TAG) ? 0.f : NEGV;
  __syncthreads();
  for (int s = 0; s < SS; ++s) {
    if (lane < NTAG) {
      float best = fv[0] + tr[lane][0]; int arg = 0;
#pragma unroll
      for (int j = 1; j < NTAG; ++j) {
        float vv = fv[j] + tr[lane][j];
        if (vv > best) { best = vv; arg = j; }
      }
      fnew[lane] = best + feats[((size_t)s * BB + b) * NTAG + lane];
      bp[s][lane] = (unsigned char)arg;
    }
    __syncthreads();
    if (lane < NTAG) fv[lane] = fnew[lane];
    __syncthreads();
  }
  if (lane < NTAG) {
    float vv = fv[lane] + tr[STOP_TAG][lane];
    if (lane == STOP_TAG || lane == START_TAG) vv = NEGV;
    term[lane] = vv;
  }
  __syncthreads();
  if (lane == 0) {
    float best = term[0]; int arg = 0;
    for (int j = 1; j < NTAG; ++j)
      if (term[j] > best) { best = term[j]; arg = j; }
    out[b] = best;
    int cur = arg;
    for (int s = SS - 1; s >= 0; --s) {
      out[64 + (size_t)b * SS + s] = (float)cur;
      cur = bp[s][cur];
    }
  }
}

// ---------------- launch ---------------------------------------------------
extern "C" void kernel_launch(void* const* d_in, const int* in_sizes, int n_in,
                              void* d_out, int out_size, void* d_ws, size_t ws_size,
                              hipStream_t stream) {
  (void)in_sizes; (void)n_in; (void)out_size;
  const int*   sent  = (const int*)d_in[0];
  const float* emb   = (const float*)d_in[4];
  const float* WihF  = (const float*)d_in[5];
  const float* WhhF  = (const float*)d_in[6];
  const float* bihF  = (const float*)d_in[7];
  const float* bhhF  = (const float*)d_in[8];
  const float* WihB  = (const float*)d_in[9];
  const float* WhhB  = (const float*)d_in[10];
  const float* bihB  = (const float*)d_in[11];
  const float* bhhB  = (const float*)d_in[12];
  const float* Wt    = (const float*)d_in[13];
  const float* bt    = (const float*)d_in[14];
  const float* trans = (const float*)d_in[15];
  const float* h0    = (const float*)d_in[16];
  const float* c0    = (const float*)d_in[17];
  float* out = (float*)d_out;

  char* ws = (char*)d_ws;
  // layout: flags 1KB | pre 134.2MB | region{ xpk 16MB (dead after k1)
  //         overlapped by hseq 33.5MB } | hx 256KB | feats 768KB
  unsigned int* flags = (unsigned int*)ws;
  float* pre   = (float*)(ws + 1024);
  float* hseq  = (float*)(ws + 1024 + 134217728ull);
  unsigned int* xpk = (unsigned int*)hseq;   // overlap: xpk dead before lstm
  unsigned int* hx = (unsigned int*)(ws + 1024 + 134217728ull + 33554432ull);
  float* feats = (float*)(ws + 1024 + 134217728ull + 33554432ull + 262144ull);
  if (ws_size < 168821760ull) return;

  hipMemsetAsync(flags, 0, 1024, stream);
  k0_gather<<<SS, 256, 0, stream>>>(sent, emb, xpk);
  k1_mfma<<<8192, 256, 0, stream>>>(xpk, WihF, WihB, bihF, bhhF, bihB, bhhB, pre);
  lstm_mfma<<<64, 256, 0, stream>>>(WhhF, WhhB, h0, c0, pre, hseq, hx, flags);
  k3_feats<<<SS, 256, 0, stream>>>(hseq, Wt, bt, feats);
  k4_viterbi<<<BB, 64, 0, stream>>>(feats, trans, out);
}

// Round 5
// 1596.777 us; speedup vs baseline: 3.8051x; 1.2109x over previous
//
#include <hip/hip_runtime.h>
#include <cstdint>
#include <cstddef>

#define EDIM 256
#define HID  512
#define NTAG 12
#define HDIM 256
#define BB   64
#define SS   256
#define START_TAG 10
#define STOP_TAG  11
#define NEGV (-10000.0f)
#define NWGD 32          // workgroups per direction
#define UPW  8           // h-units per WG (32 gate rows)

typedef __attribute__((ext_vector_type(8))) short bf16x8;
typedef __attribute__((ext_vector_type(4))) float f32x4;

__device__ __forceinline__ unsigned short bf16_rne(float x) {
  union { float f; unsigned u; } a; a.f = x;
  return (unsigned short)((a.u + 0x7fffu + ((a.u >> 16) & 1u)) >> 16);
}
__device__ __forceinline__ float bf16_tof(unsigned short h) {
  union { unsigned u; float f; } a; a.u = ((unsigned)h) << 16; return a.f;
}
__device__ __forceinline__ void unpack8(const unsigned* u, bf16x8& hi, bf16x8& lo) {
#pragma unroll
  for (int j = 0; j < 8; ++j) {
    hi[j] = (short)(u[j] & 0xffffu);
    lo[j] = (short)(u[j] >> 16);
  }
}
__device__ __forceinline__ void pack_hilo(const float* xf, bf16x8& hi, bf16x8& lo) {
#pragma unroll
  for (int j = 0; j < 8; ++j) {
    unsigned short hb = bf16_rne(xf[j]);
    hi[j] = (short)hb;
    lo[j] = (short)bf16_rne(xf[j] - bf16_tof(hb));
  }
}

// ---------------- K0: gather + split-bf16 pack  xpk[t][b][k] ---------------
__global__ void k0_gather(const int* __restrict__ sent,
                          const float* __restrict__ emb,
                          unsigned int* __restrict__ xpk) {
  int t = blockIdx.x;
  for (int n = threadIdx.x; n < BB * EDIM; n += 256) {
    int b = n >> 8, k = n & 255;
    int tok = sent[b * SS + t];
    float x = emb[(size_t)tok * EDIM + k];
    unsigned short hb = bf16_rne(x);
    unsigned short lb = bf16_rne(x - bf16_tof(hb));
    xpk[((size_t)t * BB + b) * EDIM + k] = (unsigned)hb | ((unsigned)lb << 16);
  }
}

// ---------------- K1: input projection via split-bf16 MFMA ----------------
__global__ void __launch_bounds__(256)
k1_mfma(const unsigned int* __restrict__ xpk,
        const float* __restrict__ WihF, const float* __restrict__ WihB,
        const float* __restrict__ bihF, const float* __restrict__ bhhF,
        const float* __restrict__ bihB, const float* __restrict__ bhhB,
        float* __restrict__ pre) {
  int blk = blockIdx.x;
  int rg = blk & 15, t = (blk >> 4) & 255, d = blk >> 12;
  const float* Wih = d ? WihB : WihF;
  const float* bi  = d ? bihB : bihF;
  const float* bh2 = d ? bhhB : bhhF;
  int tid = threadIdx.x, lane = tid & 63, v = tid >> 6;
  int l15 = lane & 15, l4 = lane >> 4;

  int Rrow = rg * 64 + v * 16 + l15;
  const float* wrow = Wih + (size_t)Rrow * EDIM;
  bf16x8 Ahi[8], Alo[8];
#pragma unroll
  for (int kk = 0; kk < 8; ++kk) {
    float4 f0 = *(const float4*)(wrow + kk * 32 + l4 * 8);
    float4 f1 = *(const float4*)(wrow + kk * 32 + l4 * 8 + 4);
    float xf[8] = {f0.x, f0.y, f0.z, f0.w, f1.x, f1.y, f1.z, f1.w};
    pack_hilo(xf, Ahi[kk], Alo[kk]);
  }
  float b4[4];
#pragma unroll
  for (int r = 0; r < 4; ++r) {
    int Racc = rg * 64 + v * 16 + l4 * 4 + r;
    b4[r] = bi[Racc] + bh2[Racc];
  }
  const unsigned int* xt = xpk + (size_t)t * BB * EDIM;
  size_t obase = ((size_t)d * SS + t) * 1024 * BB;
#pragma unroll
  for (int ct = 0; ct < 4; ++ct) {
    f32x4 acc = {b4[0], b4[1], b4[2], b4[3]};
    int col = ct * 16 + l15;
    const unsigned int* xc = xt + (size_t)col * EDIM;
#pragma unroll
    for (int kk = 0; kk < 8; ++kk) {
      uint4 q0 = *(const uint4*)(xc + kk * 32 + l4 * 8);
      uint4 q1 = *(const uint4*)(xc + kk * 32 + l4 * 8 + 4);
      unsigned u[8] = {q0.x, q0.y, q0.z, q0.w, q1.x, q1.y, q1.z, q1.w};
      bf16x8 bhf, blf;
      unpack8(u, bhf, blf);
      acc = __builtin_amdgcn_mfma_f32_16x16x32_bf16(Ahi[kk], bhf, acc, 0, 0, 0);
      acc = __builtin_amdgcn_mfma_f32_16x16x32_bf16(Ahi[kk], blf, acc, 0, 0, 0);
      acc = __builtin_amdgcn_mfma_f32_16x16x32_bf16(Alo[kk], bhf, acc, 0, 0, 0);
    }
#pragma unroll
    for (int r = 0; r < 4; ++r) {
      int Racc = rg * 64 + v * 16 + l4 * 4 + r;
      pre[obase + (size_t)Racc * BB + col] = acc[r];
    }
  }
}

// ---------------- K2: persistent BiLSTM, sentinel-in-data ring sync --------
// 64 WGs: d = bid>>5, w = bid&31. WG owns h-units [w*8,w*8+8) (32 gate rows).
// Wave v owns batch cols [v*16,v*16+16). Exchange: 4-slot ring hx[d][slot]
// [k][b]; |h|<1 => packed u32 never 0xFFFFFFFF. Consumers poll their data
// slice directly (poll IS the load). Producer order per step:
// poll -> re-arm slot (s+1)&3 (own slice) -> compute -> vmcnt(0) -> produce.
// vmcnt(0) between re-arm and produce makes sentinel visible strictly before
// produce(s) data => no consumer can ever accept stale (s-3) data.
__global__ void __launch_bounds__(256, 1)
lstm_mfma(const float* __restrict__ WhhF, const float* __restrict__ WhhB,
          const float* __restrict__ h0, const float* __restrict__ c0,
          const float* __restrict__ pre, float* __restrict__ hseq,
          unsigned int* __restrict__ hx) {
  const int bid = blockIdx.x;
  const int d = bid >> 5, w = bid & 31;
  const int tid = threadIdx.x;
  const int lane = tid & 63;
  const int v = tid >> 6;
  const int l15 = lane & 15, l4 = lane >> 4;
  const int up = tid >> 5;            // 0..7: unit (acts/produce mapping)
  const int b2 = (tid & 31) * 2;      // even batch col
  const float* Whh = d ? WhhB : WhhF;

  __shared__ float Cl[32][65];
  __shared__ float cst[UPW][BB];

  bf16x8 Ahi[2][8], Alo[2][8];
#pragma unroll
  for (int rt = 0; rt < 2; ++rt) {
    int i = rt * 16 + l15;
    int R = ((i >> 3) << 8) + w * UPW + (i & 7);
    const float* wrow = Whh + (size_t)R * HDIM;
#pragma unroll
    for (int kk = 0; kk < 8; ++kk) {
      float4 f0 = *(const float4*)(wrow + kk * 32 + l4 * 8);
      float4 f1 = *(const float4*)(wrow + kk * 32 + l4 * 8 + 4);
      float xf[8] = {f0.x, f0.y, f0.z, f0.w, f1.x, f1.y, f1.z, f1.w};
      pack_hilo(xf, Ahi[rt][kk], Alo[rt][kk]);
    }
  }
  cst[up][b2]     = c0[((size_t)d * BB + b2)     * HDIM + (w * UPW + up)];
  cst[up][b2 + 1] = c0[((size_t)d * BB + b2 + 1) * HDIM + (w * UPW + up)];
  __syncthreads();

  const int bcol = v * 16 + l15;
  const int kg = w * UPW + up;

  for (int s = 0; s < SS; ++s) {
    const int t = d ? (SS - 1 - s) : s;

    // acc init from pre — issued BEFORE the poll to hide HBM latency
    const float* pbase = pre + (((size_t)d * SS + t) * 1024) * BB + bcol;
    f32x4 acc0, acc1;
#pragma unroll
    for (int r = 0; r < 4; ++r) {
      int i0 = l4 * 4 + r;
      int R0 = ((i0 >> 3) << 8) + w * UPW + (i0 & 7);
      acc0[r] = pbase[(size_t)R0 * BB];
      int i1 = 16 + i0;
      int R1 = ((i1 >> 3) << 8) + w * UPW + (i1 & 7);
      acc1[r] = pbase[(size_t)R1 * BB];
    }

    // ---- data-poll: h_{s-1} straight into registers
    unsigned uv[64];
    if (s > 0) {
      const unsigned* slot =
          hx + (((size_t)d * 4 + ((s - 1) & 3)) * HDIM) * BB + bcol;
      while (true) {
        int bad = 0;
#pragma unroll
        for (int kk = 0; kk < 8; ++kk)
#pragma unroll
          for (int j = 0; j < 8; ++j) {
            unsigned val = __hip_atomic_load(
                slot + (size_t)(kk * 32 + l4 * 8 + j) * BB,
                __ATOMIC_RELAXED, __HIP_MEMORY_SCOPE_AGENT);
            uv[kk * 8 + j] = val;
            bad |= (val == 0xFFFFFFFFu);
          }
        if (!__any(bad)) break;
        __builtin_amdgcn_s_sleep(1);
      }
      __builtin_amdgcn_sched_barrier(0);
    }

    // ---- re-arm slot (s+1)&3: sentinel own produce slice
    {
      unsigned long long* ra = (unsigned long long*)(
          hx + (((size_t)d * 4 + ((s + 1) & 3)) * HDIM + kg) * BB + b2);
      __hip_atomic_store(ra, 0xFFFFFFFFFFFFFFFFull,
                         __ATOMIC_RELAXED, __HIP_MEMORY_SCOPE_AGENT);
    }

    // ---- MFMA over K=256 (split bf16: hi*hi + hi*lo + lo*hi)
    if (s == 0) {
      const float* hrow = h0 + ((size_t)d * BB + bcol) * HDIM;
#pragma unroll
      for (int kk = 0; kk < 8; ++kk) {
        float4 f0 = *(const float4*)(hrow + kk * 32 + l4 * 8);
        float4 f1 = *(const float4*)(hrow + kk * 32 + l4 * 8 + 4);
        float xf[8] = {f0.x, f0.y, f0.z, f0.w, f1.x, f1.y, f1.z, f1.w};
        bf16x8 bh, bl;
        pack_hilo(xf, bh, bl);
        acc0 = __builtin_amdgcn_mfma_f32_16x16x32_bf16(Ahi[0][kk], bh, acc0, 0, 0, 0);
        acc0 = __builtin_amdgcn_mfma_f32_16x16x32_bf16(Ahi[0][kk], bl, acc0, 0, 0, 0);
        acc0 = __builtin_amdgcn_mfma_f32_16x16x32_bf16(Alo[0][kk], bh, acc0, 0, 0, 0);
        acc1 = __builtin_amdgcn_mfma_f32_16x16x32_bf16(Ahi[1][kk], bh, acc1, 0, 0, 0);
        acc1 = __builtin_amdgcn_mfma_f32_16x16x32_bf16(Ahi[1][kk], bl, acc1, 0, 0, 0);
        acc1 = __builtin_amdgcn_mfma_f32_16x16x32_bf16(Alo[1][kk], bh, acc1, 0, 0, 0);
      }
    } else {
#pragma unroll
      for (int kk = 0; kk < 8; ++kk) {
        bf16x8 bh, bl;
        unpack8(&uv[kk * 8], bh, bl);
        acc0 = __builtin_amdgcn_mfma_f32_16x16x32_bf16(Ahi[0][kk], bh, acc0, 0, 0, 0);
        acc0 = __builtin_amdgcn_mfma_f32_16x16x32_bf16(Ahi[0][kk], bl, acc0, 0, 0, 0);
        acc0 = __builtin_amdgcn_mfma_f32_16x16x32_bf16(Alo[0][kk], bh, acc0, 0, 0, 0);
        acc1 = __builtin_amdgcn_mfma_f32_16x16x32_bf16(Ahi[1][kk], bh, acc1, 0, 0, 0);
        acc1 = __builtin_amdgcn_mfma_f32_16x16x32_bf16(Ahi[1][kk], bl, acc1, 0, 0, 0);
        acc1 = __builtin_amdgcn_mfma_f32_16x16x32_bf16(Alo[1][kk], bh, acc1, 0, 0, 0);
      }
    }

#pragma unroll
    for (int r = 0; r < 4; ++r) {
      Cl[l4 * 4 + r][bcol] = acc0[r];
      Cl[16 + l4 * 4 + r][bcol] = acc1[r];
    }
    __syncthreads();

    // ---- activations: thread (up, b2) handles cols b2, b2+1 of unit up
    float hn[2]; unsigned pv[2];
#pragma unroll
    for (int e = 0; e < 2; ++e) {
      int b = b2 + e;
      float iv = Cl[up][b], fv = Cl[8 + up][b];
      float gv = Cl[16 + up][b], ov = Cl[24 + up][b];
      float si = 1.f / (1.f + expf(-iv));
      float sf = 1.f / (1.f + expf(-fv));
      float so = 1.f / (1.f + expf(-ov));
      float cn = sf * cst[up][b] + si * tanhf(gv);
      cst[up][b] = cn;
      float h = so * tanhf(cn);
      hn[e] = h;
      unsigned short hb = bf16_rne(h);
      unsigned short lb = bf16_rne(h - bf16_tof(hb));
      pv[e] = (unsigned)hb | ((unsigned)lb << 16);
    }
    *(float2*)&hseq[(((size_t)d * SS + t) * HDIM + kg) * BB + b2] =
        make_float2(hn[0], hn[1]);

    // drain re-arm (and everything) BEFORE produce becomes visible
    asm volatile("s_waitcnt vmcnt(0)" ::: "memory");

    unsigned long long pv64 =
        (unsigned long long)pv[0] | ((unsigned long long)pv[1] << 32);
    unsigned long long* pd = (unsigned long long*)(
        hx + (((size_t)d * 4 + (s & 3)) * HDIM + kg) * BB + b2);
    __hip_atomic_store(pd, pv64, __ATOMIC_RELAXED, __HIP_MEMORY_SCOPE_AGENT);
  }
}

// ---------------- K3: feats[t][b][tag] = [hf;hb] . Wt[tag] + bt -----------
__global__ void k3_feats(const float* __restrict__ hseq,
                         const float* __restrict__ Wt,
                         const float* __restrict__ bt,
                         float* __restrict__ feats) {
  int t = blockIdx.x, tid = threadIdx.x;
  __shared__ float Wl[NTAG][HID];
  for (int n = tid; n < NTAG * HID; n += 256) Wl[n >> 9][n & 511] = Wt[n];
  __syncthreads();
  int b = tid & 63, tq = tid >> 6;
  float acc[3];
  for (int c = 0; c < 3; ++c) acc[c] = bt[tq * 3 + c];
  const float* hf = hseq + ((size_t)0 * SS + t) * HDIM * BB;
  const float* hb = hseq + ((size_t)1 * SS + t) * HDIM * BB;
  for (int k = 0; k < HDIM; ++k) {
    float h1 = hf[(size_t)k * BB + b];
    float h2 = hb[(size_t)k * BB + b];
#pragma unroll
    for (int c = 0; c < 3; ++c) {
      acc[c] += h1 * Wl[tq * 3 + c][k];
      acc[c] += h2 * Wl[tq * 3 + c][HDIM + k];
    }
  }
  for (int c = 0; c < 3; ++c)
    feats[((size_t)t * BB + b) * NTAG + tq * 3 + c] = acc[c];
}

// ---------------- K4: Viterbi per batch element ---------------------------
__global__ void k4_viterbi(const float* __restrict__ feats,
                           const float* __restrict__ trans,
                           float* __restrict__ out) {
  int b = blockIdx.x, lane = threadIdx.x;   // 64 threads
  __shared__ float tr[NTAG][NTAG];
  __shared__ float fv[NTAG], fnew[NTAG], term[NTAG];
  __shared__ unsigned char bp[SS][NTAG];
  for (int n = lane; n < NTAG * NTAG; n += 64) tr[n / NTAG][n % NTAG] = trans[n];
  if (lane < NTAG) fv[lane] = (lane == START_TAG) ? 0.f : NEGV;
  __syncthreads();
  for (int s = 0; s < SS; ++s) {
    if (lane < NTAG) {
      float best = fv[0] + tr[lane][0]; int arg = 0;
#pragma unroll
      for (int j = 1; j < NTAG; ++j) {
        float vv = fv[j] + tr[lane][j];
        if (vv > best) { best = vv; arg = j; }
      }
      fnew[lane] = best + feats[((size_t)s * BB + b) * NTAG + lane];
      bp[s][lane] = (unsigned char)arg;
    }
    __syncthreads();
    if (lane < NTAG) fv[lane] = fnew[lane];
    __syncthreads();
  }
  if (lane < NTAG) {
    float vv = fv[lane] + tr[STOP_TAG][lane];
    if (lane == STOP_TAG || lane == START_TAG) vv = NEGV;
    term[lane] = vv;
  }
  __syncthreads();
  if (lane == 0) {
    float best = term[0]; int arg = 0;
    for (int j = 1; j < NTAG; ++j)
      if (term[j] > best) { best = term[j]; arg = j; }
    out[b] = best;
    int cur = arg;
    for (int s = SS - 1; s >= 0; --s) {
      out[64 + (size_t)b * SS + s] = (float)cur;
      cur = bp[s][cur];
    }
  }
}

// ---------------- launch ---------------------------------------------------
extern "C" void kernel_launch(void* const* d_in, const int* in_sizes, int n_in,
                              void* d_out, int out_size, void* d_ws, size_t ws_size,
                              hipStream_t stream) {
  (void)in_sizes; (void)n_in; (void)out_size;
  const int*   sent  = (const int*)d_in[0];
  const float* emb   = (const float*)d_in[4];
  const float* WihF  = (const float*)d_in[5];
  const float* WhhF  = (const float*)d_in[6];
  const float* bihF  = (const float*)d_in[7];
  const float* bhhF  = (const float*)d_in[8];
  const float* WihB  = (const float*)d_in[9];
  const float* WhhB  = (const float*)d_in[10];
  const float* bihB  = (const float*)d_in[11];
  const float* bhhB  = (const float*)d_in[12];
  const float* Wt    = (const float*)d_in[13];
  const float* bt    = (const float*)d_in[14];
  const float* trans = (const float*)d_in[15];
  const float* h0    = (const float*)d_in[16];
  const float* c0    = (const float*)d_in[17];
  float* out = (float*)d_out;

  char* ws = (char*)d_ws;
  // layout: hx ring 512KB | pre 134.2MB | region{ xpk 16MB (dead after k1)
  //         overlapped by hseq 33.5MB } | feats 768KB
  unsigned int* hx = (unsigned int*)ws;                 // 2*4*256*64*4 = 512KB
  float* pre   = (float*)(ws + 524288ull);
  float* hseq  = (float*)(ws + 524288ull + 134217728ull);
  unsigned int* xpk = (unsigned int*)hseq;   // overlap: xpk dead before lstm
  float* feats = (float*)(ws + 524288ull + 134217728ull + 33554432ull);
  if (ws_size < 169082880ull) return;

  hipMemsetAsync(hx, 0xFF, 524288ull, stream);   // arm all ring slots
  k0_gather<<<SS, 256, 0, stream>>>(sent, emb, xpk);
  k1_mfma<<<8192, 256, 0, stream>>>(xpk, WihF, WihB, bihF, bhhF, bihB, bhhB, pre);
  lstm_mfma<<<64, 256, 0, stream>>>(WhhF, WhhB, h0, c0, pre, hseq, hx);
  k3_feats<<<SS, 256, 0, stream>>>(hseq, Wt, bt, feats);
  k4_viterbi<<<BB, 64, 0, stream>>>(feats, trans, out);
}